// Round 4
// baseline (1101.133 us; speedup 1.0000x reference)
//
#include <hip/hip_runtime.h>

#define B_ 256
#define T_ 128
#define E_ 512
#define H_ 512
#define NG 2048   // 4*H_
#define NB 256    // persistent blocks
#define NT 512    // threads per block (8 waves)

typedef __attribute__((ext_vector_type(8))) short bf16x8;
typedef __attribute__((ext_vector_type(4))) float f32x4;
typedef unsigned long long u64;

__device__ __forceinline__ short f2bf(float f) {
  union { float f; unsigned u; } x; x.f = f;
  unsigned r = x.u + 0x7FFFu + ((x.u >> 16) & 1u);  // RNE
  return (short)(r >> 16);
}
__device__ __forceinline__ float bf2f(short s) {
  union { unsigned u; float f; } x;
  x.u = ((unsigned)(unsigned short)s) << 16; return x.f;
}
__device__ __forceinline__ float sigm(float x) { return 1.0f / (1.0f + __expf(-x)); }
__device__ __forceinline__ float tanh_(float x) {
  float cx = fminf(fmaxf(x, -9.f), 9.f);      // clamp so exp never overflows
  float e = __expf(2.f * cx);
  return (e - 1.f) / (e + 1.f);
}

// ---- Wt[j][k] = bf16( k<512 ? Wx[k][j] : Uh[k-512][j] )
__global__ __launch_bounds__(256) void prep_w(const float* __restrict__ Wx,
                                              const float* __restrict__ Uh,
                                              short* __restrict__ Wt) {
  __shared__ float tile[64][65];
  const int k0 = blockIdx.x * 64;   // 16 blocks
  const int j0 = blockIdx.y * 64;   // 32 blocks
  const int tx = threadIdx.x & 63, ty = threadIdx.x >> 6;
#pragma unroll
  for (int r = 0; r < 16; ++r) {
    int k = k0 + r * 4 + ty;
    float v = (k < 512) ? Wx[(size_t)k * NG + j0 + tx]
                        : Uh[(size_t)(k - 512) * NG + j0 + tx];
    tile[r * 4 + ty][tx] = v;
  }
  __syncthreads();
#pragma unroll
  for (int r = 0; r < 16; ++r) {
    int j = j0 + r * 4 + ty;
    Wt[(size_t)j * 1024 + k0 + tx] = f2bf(tile[tx][r * 4 + ty]);
  }
}

// ---- xs[t][b][e] = bf16(emb[captions[b][t]][e]); padding_idx=0 row zeroed
__global__ __launch_bounds__(256) void stage_x(const int* __restrict__ captions,
                                               const float* __restrict__ emb,
                                               short* __restrict__ xs) {
  const int bid = blockIdx.x;          // = t*B_ + b
  const int t = bid >> 8, b = bid & 255;
  const int tok = captions[b * T_ + t];
  short* o = xs + (size_t)bid * E_;
  const float* src = emb + (size_t)tok * E_;
  int e0 = threadIdx.x, e1 = threadIdx.x + 256;
  if (tok) { o[e0] = f2bf(src[e0]); o[e1] = f2bf(src[e1]); }
  else     { o[e0] = 0;             o[e1] = 0; }
}

// ---- persistent kernel: all 128 LSTM steps.
// grid 256 = 8 m-groups (mg = bid&7, 32 batch rows) x 32 j-tiles (16 hidden cols).
// Waves: (mh in {0,1}) x (kq in {0..3} K-quarters); each wave does 4 gate tiles
// over its 256-wide K slice. Weights live in REGISTERS (32 bf16x8 frags/wave).
// h exchanged as tagged u64 words {tag=t+1 | 2xbf16} via relaxed agent atomics:
// the data IS the flag -> no fences, no vmcnt drain, no separate flag round-trip.
// 2 buffers suffice: a block writes h_t only after verifying ALL of h_{t-1},
// which (via each writer's block barrier) implies all group blocks finished
// reading h_{t-2}, so overwriting buffer t&1 is race-free.
__global__ __launch_bounds__(NT, 2) void lstm_all(
    const short* __restrict__ xs,   // [T][B][E] bf16
    const short* __restrict__ Wt,   // [2048][1024] bf16
    const float* __restrict__ bx, const float* __restrict__ bu,
    u64* __restrict__ hb0, u64* __restrict__ hb1) {
  __shared__ float red[2][3][4][16][17];   // [mh][slot][gate][row][col] ~26 KB
  __shared__ float gbuf[2][4][16][17];     // ~8.7 KB

  const int tid = threadIdx.x;
  const int wid = tid >> 6, lane = tid & 63;
  const int l15 = lane & 15, l4 = lane >> 4;
  const int mh = wid & 1, kq = wid >> 1;
  const int mg = blockIdx.x & 7, jt = blockIdx.x >> 3;
  const int j0 = jt * 16;
  const int rA = mg * 32 + mh * 16 + l15;

  // ---- persistent B fragments: 4 gates x 8 ks, held in VGPRs for all steps
  bf16x8 bfr[4][8];
#pragma unroll
  for (int g = 0; g < 4; ++g) {
    const short* wp = Wt + (size_t)(g * 512 + j0 + l15) * 1024 + kq * 256 + l4 * 8;
#pragma unroll
    for (int ks = 0; ks < 8; ++ks)
      bfr[g][ks] = *(const bf16x8*)(wp + ks * 32);
  }

  // ---- per-thread gate-math constants & cell state
  const int mh2 = tid >> 8, rr = (tid >> 4) & 15, jj = tid & 15;
  const int J = j0 + jj;
  const float bi  = bx[J] + bu[J];
  const float bf_ = bx[512 + J] + bu[512 + J];
  const float bo  = bx[1024 + J] + bu[1024 + J];
  const float bg  = bx[1536 + J] + bu[1536 + J];
  const int Rrow = mg * 32 + mh2 * 16 + rr;
  const int hpk = Rrow * 256 + ((j0 + (jj & ~1)) >> 1);
  float c_reg = 0.f;

  for (int t = 0; t < T_; ++t) {
    u64* hout = (t & 1) ? hb1 : hb0;
    const u64* hin = (t & 1) ? hb0 : hb1;   // h_{t-1} lives in buffer (t-1)&1

    f32x4 acc[4] = {{0,0,0,0},{0,0,0,0},{0,0,0,0},{0,0,0,0}};

    if (kq < 2) {
      // ---- x half of K (always ready)
      const short* ab = xs + ((size_t)t * B_ + rA) * E_ + kq * 256 + l4 * 8;
      bf16x8 af[8];
#pragma unroll
      for (int ks = 0; ks < 8; ++ks) af[ks] = *(const bf16x8*)(ab + ks * 32);
#pragma unroll
      for (int ks = 0; ks < 8; ++ks)
#pragma unroll
        for (int g = 0; g < 4; ++g)
          acc[g] = __builtin_amdgcn_mfma_f32_16x16x32_bf16(af[ks], bfr[g][ks], acc[g], 0, 0, 0);
    } else if (t > 0) {
      // ---- h half: poll-load tagged words (tag == t means h_{t-1} is there)
      const u64* hp = hin + (size_t)rA * 256 + (kq - 2) * 128 + l4 * 4;
      const unsigned exp_ = (unsigned)t;
      u64 w[32];
#pragma unroll
      for (int ks = 0; ks < 8; ++ks)
#pragma unroll
        for (int i = 0; i < 4; ++i)
          w[ks * 4 + i] = __hip_atomic_load(hp + ks * 16 + i,
                                            __ATOMIC_RELAXED, __HIP_MEMORY_SCOPE_AGENT);
#pragma unroll
      for (int ks = 0; ks < 8; ++ks)
#pragma unroll
        for (int i = 0; i < 4; ++i) {
          u64 v = w[ks * 4 + i];
          while ((unsigned)(v >> 32) != exp_)
            v = __hip_atomic_load(hp + ks * 16 + i,
                                  __ATOMIC_RELAXED, __HIP_MEMORY_SCOPE_AGENT);
          w[ks * 4 + i] = v;
        }
#pragma unroll
      for (int ks = 0; ks < 8; ++ks) {
        union { bf16x8 v; unsigned u[4]; } fa;
#pragma unroll
        for (int i = 0; i < 4; ++i) fa.u[i] = (unsigned)w[ks * 4 + i];
#pragma unroll
        for (int g = 0; g < 4; ++g)
          acc[g] = __builtin_amdgcn_mfma_f32_16x16x32_bf16(fa.v, bfr[g][ks], acc[g], 0, 0, 0);
      }
    }
    // (kq>=2, t==0: h_{-1}=0 -> zero contribution, acc stays 0)

    // ---- K-quarter reduction: one LDS round
    if (kq) {
#pragma unroll
      for (int g = 0; g < 4; ++g)
#pragma unroll
        for (int r = 0; r < 4; ++r)
          red[mh][kq - 1][g][l4 * 4 + r][l15] = acc[g][r];
    }
    __syncthreads();                                   // SYNC1
    if (kq == 0) {
#pragma unroll
      for (int g = 0; g < 4; ++g)
#pragma unroll
        for (int r = 0; r < 4; ++r)
          gbuf[mh][g][l4 * 4 + r][l15] = acc[g][r]
              + red[mh][0][g][l4 * 4 + r][l15]
              + red[mh][1][g][l4 * 4 + r][l15]
              + red[mh][2][g][l4 * 4 + r][l15];
    }
    __syncthreads();                                   // SYNC2

    // ---- gate math; c in registers; h -> tagged u64, relaxed agent store
    {
      float iv = gbuf[mh2][0][rr][jj] + bi;
      float fv = gbuf[mh2][1][rr][jj] + bf_;
      float ov = gbuf[mh2][2][rr][jj] + bo;
      float gv = gbuf[mh2][3][rr][jj] + bg;
      float cn = sigm(fv) * c_reg + sigm(iv) * tanh_(gv);
      c_reg = cn;
      unsigned mine = (unsigned)(unsigned short)f2bf(sigm(ov) * tanh_(cn));
      unsigned other = (unsigned)__shfl_xor((int)mine, 1, 64);
      if (!(jj & 1)) {
        u64 val = (u64)(mine | (other << 16)) | (((u64)(unsigned)(t + 1)) << 32);
        __hip_atomic_store(&hout[hpk], val, __ATOMIC_RELAXED, __HIP_MEMORY_SCOPE_AGENT);
      }
    }
    // no end-of-step barrier needed: red(t+1) writes happen after SYNC2(t),
    // gbuf(t+1) writes happen after SYNC1(t+1).
  }
}

// ---- out[b,:] = normalize( h_last[b,:] @ fcW + fcb ); h is the tagged u64 buffer
__global__ __launch_bounds__(256) void final_fc(const u64* __restrict__ h,
                                                const float* __restrict__ fcW,
                                                const float* __restrict__ fcb,
                                                float* __restrict__ out) {
  const int b = blockIdx.x, tid = threadIdx.x;
  __shared__ float hrow[512];
  __shared__ float red[256];
  {
    u64 w = h[(size_t)b * 256 + tid];
    hrow[tid * 2]     = bf2f((short)(w & 0xFFFF));
    hrow[tid * 2 + 1] = bf2f((short)((w >> 16) & 0xFFFF));
  }
  __syncthreads();
  float a0 = fcb[tid], a1 = fcb[tid + 256];
  for (int k = 0; k < 512; ++k) {
    float hv = hrow[k];
    a0 += hv * fcW[(size_t)k * 512 + tid];
    a1 += hv * fcW[(size_t)k * 512 + tid + 256];
  }
  red[tid] = a0 * a0 + a1 * a1;
  __syncthreads();
  for (int s = 128; s > 0; s >>= 1) {
    if (tid < s) red[tid] += red[tid + s];
    __syncthreads();
  }
  float scale = 1.0f / fmaxf(sqrtf(red[0]), 1e-12f);
  out[(size_t)b * 512 + tid] = a0 * scale;
  out[(size_t)b * 512 + tid + 256] = a1 * scale;
}

extern "C" void kernel_launch(void* const* d_in, const int* in_sizes, int n_in,
                              void* d_out, int out_size, void* d_ws, size_t ws_size,
                              hipStream_t stream) {
  const int*   captions = (const int*)d_in[0];
  const float* emb      = (const float*)d_in[1];
  const float* Wx       = (const float*)d_in[2];
  const float* bx       = (const float*)d_in[3];
  const float* Uh       = (const float*)d_in[4];
  const float* bu       = (const float*)d_in[5];
  const float* fcW      = (const float*)d_in[6];
  const float* fcb      = (const float*)d_in[7];
  float* out = (float*)d_out;

  char* ws = (char*)d_ws;
  size_t off = 0;
  auto alloc = [&](size_t bytes) {
    char* p = ws + off;
    off += (bytes + 255) & ~(size_t)255;
    return p;
  };
  short* Wt  = (short*)alloc((size_t)NG * 1024 * 2);     // 4 MB
  short* xs  = (short*)alloc((size_t)T_ * B_ * E_ * 2);  // 32 MB
  u64*   hb0 = (u64*)alloc((size_t)B_ * 256 * 8);        // 512 KB (tagged)
  u64*   hb1 = (u64*)alloc((size_t)B_ * 256 * 8);        // 512 KB

  // zero tags every launch: no state may carry across calls (harness rule),
  // and stale tags would short-circuit the recurrence synchronization.
  hipMemsetAsync(hb0, 0, (size_t)B_ * 256 * 8, stream);
  hipMemsetAsync(hb1, 0, (size_t)B_ * 256 * 8, stream);

  prep_w<<<dim3(16, 32), 256, 0, stream>>>(Wx, Uh, Wt);
  stage_x<<<T_ * B_, 256, 0, stream>>>(captions, emb, xs);

  void* kargs[] = {(void*)&xs, (void*)&Wt, (void*)&bx, (void*)&bu,
                   (void*)&hb0, (void*)&hb1};
  hipLaunchCooperativeKernel((const void*)lstm_all, dim3(NB), dim3(NT),
                             kargs, 0, stream);

  // t=127 wrote buffer 127&1 = hb1
  final_fc<<<B_, 256, 0, stream>>>(hb1, fcW, fcb, out);
}

// Round 5
// 931.345 us; speedup vs baseline: 1.1823x; 1.1823x over previous
//
#include <hip/hip_runtime.h>

#define B_ 256
#define T_ 128
#define E_ 512
#define H_ 512
#define NG 2048   // 4*H_
#define NB 256    // persistent blocks
#define NT 512    // threads per block (8 waves)

typedef __attribute__((ext_vector_type(8))) short bf16x8;
typedef __attribute__((ext_vector_type(4))) float f32x4;
typedef unsigned long long u64;

__device__ __forceinline__ short f2bf(float f) {
  union { float f; unsigned u; } x; x.f = f;
  unsigned r = x.u + 0x7FFFu + ((x.u >> 16) & 1u);  // RNE
  return (short)(r >> 16);
}
__device__ __forceinline__ float bf2f(short s) {
  union { unsigned u; float f; } x;
  x.u = ((unsigned)(unsigned short)s) << 16; return x.f;
}
__device__ __forceinline__ float sigm(float x) { return 1.0f / (1.0f + __expf(-x)); }
__device__ __forceinline__ float tanh_(float x) {
  float cx = fminf(fmaxf(x, -9.f), 9.f);
  float e = __expf(2.f * cx);
  return (e - 1.f) / (e + 1.f);
}

// ---- Wt[j][k] = bf16( k<512 ? Wx[k][j] : Uh[k-512][j] )
__global__ __launch_bounds__(256) void prep_w(const float* __restrict__ Wx,
                                              const float* __restrict__ Uh,
                                              short* __restrict__ Wt) {
  __shared__ float tile[64][65];
  const int k0 = blockIdx.x * 64;   // 16 blocks
  const int j0 = blockIdx.y * 64;   // 32 blocks
  const int tx = threadIdx.x & 63, ty = threadIdx.x >> 6;
#pragma unroll
  for (int r = 0; r < 16; ++r) {
    int k = k0 + r * 4 + ty;
    float v = (k < 512) ? Wx[(size_t)k * NG + j0 + tx]
                        : Uh[(size_t)(k - 512) * NG + j0 + tx];
    tile[r * 4 + ty][tx] = v;
  }
  __syncthreads();
#pragma unroll
  for (int r = 0; r < 16; ++r) {
    int j = j0 + r * 4 + ty;
    Wt[(size_t)j * 1024 + k0 + tx] = f2bf(tile[tx][r * 4 + ty]);
  }
}

// ---- xs[t][b][e] = bf16(emb[captions[b][t]][e]); padding_idx=0 row zeroed
__global__ __launch_bounds__(256) void stage_x(const int* __restrict__ captions,
                                               const float* __restrict__ emb,
                                               short* __restrict__ xs) {
  const int bid = blockIdx.x;          // = t*B_ + b
  const int t = bid >> 8, b = bid & 255;
  const int tok = captions[b * T_ + t];
  short* o = xs + (size_t)bid * E_;
  const float* src = emb + (size_t)tok * E_;
  int e0 = threadIdx.x, e1 = threadIdx.x + 256;
  if (tok) { o[e0] = f2bf(src[e0]); o[e1] = f2bf(src[e1]); }
  else     { o[e0] = 0;             o[e1] = 0; }
}

// ---- persistent kernel: all 128 LSTM steps.
// grid 256 = 8 m-groups (mg = bid&7, 32 batch rows) x 32 j-tiles (16 hidden cols).
// Waves: (mh in {0,1}) x (kq in {0..3} K-quarters). Weights pinned in VGPRs via
// inline-asm keep-alive (32 bf16x8 = 128 VGPRs/wave). h exchanged as tagged u64
// {tag=t+1 | 2xbf16} relaxed agent atomics; readers use PARALLEL retry rounds
// (reload all stale words of a chunk concurrently), not per-word serial spins.
// 2 buffers suffice: a block writes h_t only after verifying ALL of h_{t-1},
// which (via its block barrier) implies all group blocks finished h_{t-2} reads.
__global__ __launch_bounds__(NT, 2) void lstm_all(
    const short* __restrict__ xs,   // [T][B][E] bf16
    const short* __restrict__ Wt,   // [2048][1024] bf16
    const float* __restrict__ bx, const float* __restrict__ bu,
    u64* __restrict__ hb0, u64* __restrict__ hb1) {
  __shared__ float red[2][3][4][16][20];   // [mh][slot][gate][row][col20] 30.7 KB
  __shared__ float gbuf[2][4][16][20];     // 10.2 KB

  const int tid = threadIdx.x;
  const int wid = tid >> 6, lane = tid & 63;
  const int l15 = lane & 15, l4 = lane >> 4;
  const int mh = wid & 1, kq = wid >> 1;
  const int mg = blockIdx.x & 7, jt = blockIdx.x >> 3;
  const int j0 = jt * 16;
  const int rA = mg * 32 + mh * 16 + l15;

  // ---- persistent B fragments: 4 gates x 8 ks, pinned in VGPRs for all steps
  bf16x8 bfr[4][8];
#pragma unroll
  for (int g = 0; g < 4; ++g) {
    const short* wp = Wt + (size_t)(g * 512 + j0 + l15) * 1024 + kq * 256 + l4 * 8;
#pragma unroll
    for (int ks = 0; ks < 8; ++ks)
      bfr[g][ks] = *(const bf16x8*)(wp + ks * 32);
  }
#pragma unroll
  for (int g = 0; g < 4; ++g)
#pragma unroll
    for (int ks = 0; ks < 8; ++ks)
      asm volatile("" : "+v"(bfr[g][ks]));   // sever rematerialization

  // ---- per-thread gate-math constants & cell state
  const int mh2 = tid >> 8, rr = (tid >> 4) & 15, jj = tid & 15;
  const int J = j0 + jj;
  const float bi  = bx[J] + bu[J];
  const float bf_ = bx[512 + J] + bu[512 + J];
  const float bo  = bx[1024 + J] + bu[1024 + J];
  const float bg  = bx[1536 + J] + bu[1536 + J];
  const int Rrow = mg * 32 + mh2 * 16 + rr;
  const int hpk = Rrow * 256 + ((j0 + (jj & ~1)) >> 1);
  float c_reg = 0.f;

  for (int t = 0; t < T_; ++t) {
    u64* hout = (t & 1) ? hb1 : hb0;
    const u64* hin = (t & 1) ? hb0 : hb1;   // h_{t-1} lives in buffer (t-1)&1

    f32x4 acc[4] = {{0,0,0,0},{0,0,0,0},{0,0,0,0},{0,0,0,0}};

    if (kq < 2) {
      // ---- x half of K (always ready)
      const short* ab = xs + ((size_t)t * B_ + rA) * E_ + kq * 256 + l4 * 8;
      bf16x8 af[8];
#pragma unroll
      for (int ks = 0; ks < 8; ++ks) af[ks] = *(const bf16x8*)(ab + ks * 32);
#pragma unroll
      for (int ks = 0; ks < 8; ++ks)
#pragma unroll
        for (int g = 0; g < 4; ++g)
          acc[g] = __builtin_amdgcn_mfma_f32_16x16x32_bf16(af[ks], bfr[g][ks], acc[g], 0, 0, 0);
    } else if (t > 0) {
      // ---- h half: tagged words, parallel-retry verify, 2 chunks of 16 u64
      const u64* hp = hin + (size_t)rA * 256 + (kq - 2) * 128 + l4 * 4;
      const unsigned exp_ = (unsigned)t;
#pragma unroll
      for (int half = 0; half < 2; ++half) {
        u64 w[16];
#pragma unroll
        for (int q = 0; q < 16; ++q)
          w[q] = __hip_atomic_load(hp + (half * 4 + (q >> 2)) * 16 + (q & 3),
                                   __ATOMIC_RELAXED, __HIP_MEMORY_SCOPE_AGENT);
        bool ok = false;
        while (!ok) {
          ok = true;
#pragma unroll
          for (int q = 0; q < 16; ++q) {
            if ((unsigned)(w[q] >> 32) != exp_) {
              w[q] = __hip_atomic_load(hp + (half * 4 + (q >> 2)) * 16 + (q & 3),
                                       __ATOMIC_RELAXED, __HIP_MEMORY_SCOPE_AGENT);
              ok = false;
            }
          }
        }
#pragma unroll
        for (int ks = 0; ks < 4; ++ks) {
          union { bf16x8 v; unsigned u[4]; } fa;
#pragma unroll
          for (int i = 0; i < 4; ++i) fa.u[i] = (unsigned)w[ks * 4 + i];
#pragma unroll
          for (int g = 0; g < 4; ++g)
            acc[g] = __builtin_amdgcn_mfma_f32_16x16x32_bf16(
                fa.v, bfr[g][half * 4 + ks], acc[g], 0, 0, 0);
        }
      }
    }
    // (kq>=2, t==0: h_{-1}=0 -> zero contribution)

    // ---- K-quarter reduction: one LDS round
    if (kq) {
#pragma unroll
      for (int g = 0; g < 4; ++g)
#pragma unroll
        for (int r = 0; r < 4; ++r)
          red[mh][kq - 1][g][l4 * 4 + r][l15] = acc[g][r];
    }
    __syncthreads();                                   // SYNC1
    if (kq == 0) {
#pragma unroll
      for (int g = 0; g < 4; ++g)
#pragma unroll
        for (int r = 0; r < 4; ++r)
          gbuf[mh][g][l4 * 4 + r][l15] = acc[g][r]
              + red[mh][0][g][l4 * 4 + r][l15]
              + red[mh][1][g][l4 * 4 + r][l15]
              + red[mh][2][g][l4 * 4 + r][l15];
    }
    __syncthreads();                                   // SYNC2

    // ---- gate math; c in registers; h -> tagged u64, relaxed agent store
    {
      float iv = gbuf[mh2][0][rr][jj] + bi;
      float fv = gbuf[mh2][1][rr][jj] + bf_;
      float ov = gbuf[mh2][2][rr][jj] + bo;
      float gv = gbuf[mh2][3][rr][jj] + bg;
      float cn = sigm(fv) * c_reg + sigm(iv) * tanh_(gv);
      c_reg = cn;
      unsigned mine = (unsigned)(unsigned short)f2bf(sigm(ov) * tanh_(cn));
      unsigned other = (unsigned)__shfl_xor((int)mine, 1, 64);
      if (!(jj & 1)) {
        u64 val = (u64)(mine | (other << 16)) | (((u64)(unsigned)(t + 1)) << 32);
        __hip_atomic_store(&hout[hpk], val, __ATOMIC_RELAXED, __HIP_MEMORY_SCOPE_AGENT);
      }
    }
    // no end-of-step barrier: red(t+1) writes happen after SYNC2(t),
    // gbuf(t+1) writes happen after SYNC1(t+1).
  }
}

// ---- out[b,:] = normalize( h_last[b,:] @ fcW + fcb ); h is the tagged u64 buffer
__global__ __launch_bounds__(256) void final_fc(const u64* __restrict__ h,
                                                const float* __restrict__ fcW,
                                                const float* __restrict__ fcb,
                                                float* __restrict__ out) {
  const int b = blockIdx.x, tid = threadIdx.x;
  __shared__ float hrow[512];
  __shared__ float red[256];
  {
    u64 w = h[(size_t)b * 256 + tid];
    hrow[tid * 2]     = bf2f((short)(w & 0xFFFF));
    hrow[tid * 2 + 1] = bf2f((short)((w >> 16) & 0xFFFF));
  }
  __syncthreads();
  float a0 = fcb[tid], a1 = fcb[tid + 256];
  for (int k = 0; k < 512; ++k) {
    float hv = hrow[k];
    a0 += hv * fcW[(size_t)k * 512 + tid];
    a1 += hv * fcW[(size_t)k * 512 + tid + 256];
  }
  red[tid] = a0 * a0 + a1 * a1;
  __syncthreads();
  for (int s = 128; s > 0; s >>= 1) {
    if (tid < s) red[tid] += red[tid + s];
    __syncthreads();
  }
  float scale = 1.0f / fmaxf(sqrtf(red[0]), 1e-12f);
  out[(size_t)b * 512 + tid] = a0 * scale;
  out[(size_t)b * 512 + tid + 256] = a1 * scale;
}

extern "C" void kernel_launch(void* const* d_in, const int* in_sizes, int n_in,
                              void* d_out, int out_size, void* d_ws, size_t ws_size,
                              hipStream_t stream) {
  const int*   captions = (const int*)d_in[0];
  const float* emb      = (const float*)d_in[1];
  const float* Wx       = (const float*)d_in[2];
  const float* bx       = (const float*)d_in[3];
  const float* Uh       = (const float*)d_in[4];
  const float* bu       = (const float*)d_in[5];
  const float* fcW      = (const float*)d_in[6];
  const float* fcb      = (const float*)d_in[7];
  float* out = (float*)d_out;

  char* ws = (char*)d_ws;
  size_t off = 0;
  auto alloc = [&](size_t bytes) {
    char* p = ws + off;
    off += (bytes + 255) & ~(size_t)255;
    return p;
  };
  short* Wt  = (short*)alloc((size_t)NG * 1024 * 2);     // 4 MB
  short* xs  = (short*)alloc((size_t)T_ * B_ * E_ * 2);  // 32 MB
  u64*   hb0 = (u64*)alloc((size_t)B_ * 256 * 8);        // 512 KB (tagged)
  u64*   hb1 = (u64*)alloc((size_t)B_ * 256 * 8);

  // zero tags every launch (stale tags from a previous replay would
  // short-circuit the synchronization)
  hipMemsetAsync(hb0, 0, (size_t)B_ * 256 * 8, stream);
  hipMemsetAsync(hb1, 0, (size_t)B_ * 256 * 8, stream);

  prep_w<<<dim3(16, 32), 256, 0, stream>>>(Wx, Uh, Wt);
  stage_x<<<T_ * B_, 256, 0, stream>>>(captions, emb, xs);

  void* kargs[] = {(void*)&xs, (void*)&Wt, (void*)&bx, (void*)&bu,
                   (void*)&hb0, (void*)&hb1};
  hipLaunchCooperativeKernel((const void*)lstm_all, dim3(NB), dim3(NT),
                             kargs, 0, stream);

  // t=127 wrote buffer 127&1 = hb1
  final_fc<<<B_, 256, 0, stream>>>(hb1, fcW, fcb, out);
}